// Round 1
// baseline (500.147 us; speedup 1.0000x reference)
//
#include <hip/hip_runtime.h>

// Problem constants (fixed by setup_inputs in the reference).
#define B 8
#define C 256
#define H 128
#define W 128
#define NBOX 64
#define OUT_H 6
#define OUT_W 6
#define GH 2          // SAMPLING_RATIO
#define GW 2
#define NSY (OUT_H * GH)   // 12 sample rows per box
#define NSX (OUT_W * GW)   // 12 sample cols per box

// torchvision bilinear_interpolate 1-D helper (aligned=True path), matching
// reference _interp_1d exactly.
__device__ __forceinline__ void interp1d(float coord, int size,
                                         int& lo, int& hi,
                                         float& w0, float& w1) {
    bool valid = (coord >= -1.0f) && (coord <= (float)size);
    float c = fmaxf(coord, 0.0f);
    int low0 = (int)floorf(c);
    bool at_edge = (low0 >= size - 1);
    lo = at_edge ? (size - 1) : low0;
    hi = at_edge ? (size - 1) : (low0 + 1);
    float frac = at_edge ? 0.0f : (c - (float)low0);
    w0 = valid ? (1.0f - frac) : 0.0f;
    w1 = valid ? frac : 0.0f;
}

// One block per (b, n) box; 256 threads = one per channel.
__global__ __launch_bounds__(256)
void roi_align_kernel(const float* __restrict__ x,
                      const float* __restrict__ boxes,
                      float* __restrict__ out) {
    const int bn = blockIdx.x;          // 0 .. B*NBOX-1
    const int b = bn / NBOX;
    const int n = bn % NBOX;
    const int c = threadIdx.x;          // 0 .. 255

    // Per-box sample tables (channel-independent).
    __shared__ int   s_yl[NSY], s_yh[NSY];
    __shared__ float s_wy0[NSY], s_wy1[NSY];
    __shared__ int   s_xl[NSX], s_xh[NSX];
    __shared__ float s_wx0[NSX], s_wx1[NSX];

    const float* bx = boxes + (bn * 4);
    // aligned=True half-pixel offset; SPATIAL_SCALE = 1.0
    const float x1 = bx[0] - 0.5f;
    const float y1 = bx[1] - 0.5f;
    const float x2 = bx[2] - 0.5f;
    const float y2 = bx[3] - 0.5f;
    const float bin_h = (y2 - y1) * (1.0f / OUT_H);
    const float bin_w = (x2 - x1) * (1.0f / OUT_W);

    if (threadIdx.x < NSY) {
        int k = threadIdx.x;                    // k = oh*GH + i
        int ohb = k >> 1, i = k & 1;
        float pos = (float)ohb + ((float)i + 0.5f) * 0.5f;
        float yc = y1 + pos * bin_h;
        interp1d(yc, H, s_yl[k], s_yh[k], s_wy0[k], s_wy1[k]);
    } else if (threadIdx.x < NSY + NSX) {
        int k = threadIdx.x - NSY;              // k = ow*GW + j
        int owb = k >> 1, j = k & 1;
        float pos = (float)owb + ((float)j + 0.5f) * 0.5f;
        float xc = x1 + pos * bin_w;
        interp1d(xc, W, s_xl[k], s_xh[k], s_wx0[k], s_wx1[k]);
    }
    __syncthreads();

    const float* feat = x + ((size_t)(b * C + c) * (H * W));
    float* op = out + ((size_t)(bn * C + c) * (OUT_H * OUT_W));

    #pragma unroll
    for (int oh = 0; oh < OUT_H; ++oh) {
        // row pointers + weights for the 2 y-samples of this bin
        const int sy0 = oh * GH, sy1 = oh * GH + 1;
        const float* r00 = feat + s_yl[sy0] * W;
        const float* r01 = feat + s_yh[sy0] * W;
        const float* r10 = feat + s_yl[sy1] * W;
        const float* r11 = feat + s_yh[sy1] * W;
        const float wy00 = s_wy0[sy0], wy01 = s_wy1[sy0];
        const float wy10 = s_wy0[sy1], wy11 = s_wy1[sy1];

        #pragma unroll
        for (int ow = 0; ow < OUT_W; ++ow) {
            float v = 0.0f;
            #pragma unroll
            for (int j = 0; j < GW; ++j) {
                const int sx = ow * GW + j;
                const int xl = s_xl[sx], xh = s_xh[sx];
                const float wx0 = s_wx0[sx], wx1 = s_wx1[sx];
                // sample (i=0) row pair
                v += wy00 * (wx0 * r00[xl] + wx1 * r00[xh])
                   + wy01 * (wx0 * r01[xl] + wx1 * r01[xh]);
                // sample (i=1) row pair
                v += wy10 * (wx0 * r10[xl] + wx1 * r10[xh])
                   + wy11 * (wx0 * r11[xl] + wx1 * r11[xh]);
            }
            op[oh * OUT_W + ow] = v * 0.25f;   // mean over GH*GW samples
        }
    }
}

extern "C" void kernel_launch(void* const* d_in, const int* in_sizes, int n_in,
                              void* d_out, int out_size, void* d_ws, size_t ws_size,
                              hipStream_t stream) {
    const float* x     = (const float*)d_in[0];
    const float* boxes = (const float*)d_in[1];
    float* out = (float*)d_out;

    dim3 grid(B * NBOX);
    dim3 block(C);
    roi_align_kernel<<<grid, block, 0, stream>>>(x, boxes, out);
}

// Round 2
// 254.894 us; speedup vs baseline: 1.9622x; 1.9622x over previous
//
#include <hip/hip_runtime.h>

// Problem constants (fixed by setup_inputs in the reference).
#define B 8
#define C 256
#define H 128
#define W 128
#define HW (H * W)
#define NBOX 64
#define OUT_H 6
#define OUT_W 6
#define NSY 12            // OUT_H * sampling_ratio
#define NSX 12
#define NBINS (OUT_H * OUT_W)   // 36
#define OUT_PITCH 257     // LDS staging pitch (256 ch + 1 pad)

// torchvision bilinear_interpolate 1-D helper (aligned=True), matching
// reference _interp_1d exactly.
__device__ __forceinline__ void interp1d(float coord, int size,
                                         int& lo, int& hi,
                                         float& w0, float& w1) {
    bool valid = (coord >= -1.0f) && (coord <= (float)size);
    float c = fmaxf(coord, 0.0f);
    int low0 = (int)floorf(c);
    bool at_edge = (low0 >= size - 1);
    lo = at_edge ? (size - 1) : low0;
    hi = at_edge ? (size - 1) : (low0 + 1);
    float frac = at_edge ? 0.0f : (c - (float)low0);
    w0 = valid ? (1.0f - frac) : 0.0f;
    w1 = valid ? frac : 0.0f;
}

// ---------------------------------------------------------------------------
// NCHW -> NHWC transpose: x[B][C][HW] -> xt[B][HW][C].
// Classic 32x32 LDS tile; reads coalesced along HW, writes coalesced along C.
__global__ __launch_bounds__(256)
void transpose_kernel(const float* __restrict__ x, float* __restrict__ xt) {
    __shared__ float tile[32][33];
    const int b  = blockIdx.z;
    const int s0 = blockIdx.x * 32;   // spatial tile origin
    const int c0 = blockIdx.y * 32;   // channel tile origin
    const float* xb = x + (size_t)b * C * HW;
    float* xtb = xt + (size_t)b * HW * C;
    const int tx = threadIdx.x;       // 0..31
    const int ty = threadIdx.y;       // 0..7
    #pragma unroll
    for (int i = 0; i < 32; i += 8)
        tile[ty + i][tx] = xb[(size_t)(c0 + ty + i) * HW + (s0 + tx)];
    __syncthreads();
    #pragma unroll
    for (int i = 0; i < 32; i += 8)
        xtb[(size_t)(s0 + ty + i) * C + (c0 + tx)] = tile[tx][ty + i];
}

// ---------------------------------------------------------------------------
// RoI align on NHWC features. One block per (b,n) box.
// Block (64,4): threadIdx.x = channel-group (4 ch, float4 loads -> 1 KB/wave),
// threadIdx.y = wave, each wave handles 9 of the 36 output bins.
__global__ __launch_bounds__(256)
void roi_align_nhwc_kernel(const float* __restrict__ xt,
                           const float* __restrict__ boxes,
                           float* __restrict__ out) {
    const int bn = blockIdx.x;
    const int b = bn / NBOX;

    __shared__ int   s_yl[NSY], s_yh[NSY];
    __shared__ float s_wy0[NSY], s_wy1[NSY];
    __shared__ int   s_xl[NSX], s_xh[NSX];
    __shared__ float s_wx0[NSX], s_wx1[NSX];
    __shared__ float s_out[NBINS * OUT_PITCH];   // [bin][channel], padded

    const int tid = threadIdx.y * 64 + threadIdx.x;

    const float* bx = boxes + (bn * 4);
    const float x1 = bx[0] - 0.5f;   // SPATIAL_SCALE = 1, aligned=True offset
    const float y1 = bx[1] - 0.5f;
    const float x2 = bx[2] - 0.5f;
    const float y2 = bx[3] - 0.5f;
    const float bin_h = (y2 - y1) * (1.0f / OUT_H);
    const float bin_w = (x2 - x1) * (1.0f / OUT_W);

    if (tid < NSY) {
        int k = tid;                         // k = oh*2 + i
        float pos = (float)(k >> 1) + ((float)(k & 1) + 0.5f) * 0.5f;
        interp1d(y1 + pos * bin_h, H, s_yl[k], s_yh[k], s_wy0[k], s_wy1[k]);
    } else if (tid < NSY + NSX) {
        int k = tid - NSY;                   // k = ow*2 + j
        float pos = (float)(k >> 1) + ((float)(k & 1) + 0.5f) * 0.5f;
        interp1d(x1 + pos * bin_w, W, s_xl[k], s_xh[k], s_wx0[k], s_wx1[k]);
    }
    __syncthreads();

    const float4* ft = (const float4*)(xt + (size_t)b * HW * C);
    const int cg = threadIdx.x;              // channel group: ch = cg*4 .. cg*4+3
    const int kb0 = threadIdx.y * 9;

    for (int kk = 0; kk < 9; ++kk) {
        const int kb = kb0 + kk;             // bin index 0..35
        const int oh = kb / OUT_W, ow = kb % OUT_W;
        float4 acc = make_float4(0.f, 0.f, 0.f, 0.f);
        #pragma unroll
        for (int i = 0; i < 2; ++i) {
            const int sy = oh * 2 + i;
            const int yl = s_yl[sy], yh = s_yh[sy];
            const float wy0 = s_wy0[sy], wy1 = s_wy1[sy];
            #pragma unroll
            for (int j = 0; j < 2; ++j) {
                const int sx = ow * 2 + j;
                const int xl = s_xl[sx], xh = s_xh[sx];
                const float wx0 = s_wx0[sx], wx1 = s_wx1[sx];
                const float w00 = wy0 * wx0, w01 = wy0 * wx1;
                const float w10 = wy1 * wx0, w11 = wy1 * wx1;
                const float4 v00 = ft[(size_t)(yl * W + xl) * (C / 4) + cg];
                const float4 v01 = ft[(size_t)(yl * W + xh) * (C / 4) + cg];
                const float4 v10 = ft[(size_t)(yh * W + xl) * (C / 4) + cg];
                const float4 v11 = ft[(size_t)(yh * W + xh) * (C / 4) + cg];
                acc.x += w00 * v00.x + w01 * v01.x + w10 * v10.x + w11 * v11.x;
                acc.y += w00 * v00.y + w01 * v01.y + w10 * v10.y + w11 * v11.y;
                acc.z += w00 * v00.z + w01 * v01.z + w10 * v10.z + w11 * v11.z;
                acc.w += w00 * v00.w + w01 * v01.w + w10 * v10.w + w11 * v11.w;
            }
        }
        const int cbase = cg * 4;
        s_out[kb * OUT_PITCH + cbase + 0] = acc.x * 0.25f;
        s_out[kb * OUT_PITCH + cbase + 1] = acc.y * 0.25f;
        s_out[kb * OUT_PITCH + cbase + 2] = acc.z * 0.25f;
        s_out[kb * OUT_PITCH + cbase + 3] = acc.w * 0.25f;
    }
    __syncthreads();

    // Coalesced write-out: out region for this block is contiguous [C*36].
    float* op = out + (size_t)bn * (C * NBINS);
    #pragma unroll
    for (int it = 0; it < NBINS; ++it) {
        const int idx = it * 256 + tid;      // 0 .. 9215
        const int c = idx / NBINS, k = idx % NBINS;
        op[idx] = s_out[k * OUT_PITCH + c];
    }
}

// ---------------------------------------------------------------------------
// Fallback (round-1 kernel) if workspace is too small for the transpose.
__global__ __launch_bounds__(256)
void roi_align_nchw_kernel(const float* __restrict__ x,
                           const float* __restrict__ boxes,
                           float* __restrict__ out) {
    const int bn = blockIdx.x;
    const int b = bn / NBOX;
    const int c = threadIdx.x;

    __shared__ int   s_yl[NSY], s_yh[NSY];
    __shared__ float s_wy0[NSY], s_wy1[NSY];
    __shared__ int   s_xl[NSX], s_xh[NSX];
    __shared__ float s_wx0[NSX], s_wx1[NSX];

    const float* bx = boxes + (bn * 4);
    const float x1 = bx[0] - 0.5f;
    const float y1 = bx[1] - 0.5f;
    const float x2 = bx[2] - 0.5f;
    const float y2 = bx[3] - 0.5f;
    const float bin_h = (y2 - y1) * (1.0f / OUT_H);
    const float bin_w = (x2 - x1) * (1.0f / OUT_W);

    if (threadIdx.x < NSY) {
        int k = threadIdx.x;
        float pos = (float)(k >> 1) + ((float)(k & 1) + 0.5f) * 0.5f;
        interp1d(y1 + pos * bin_h, H, s_yl[k], s_yh[k], s_wy0[k], s_wy1[k]);
    } else if (threadIdx.x < NSY + NSX) {
        int k = threadIdx.x - NSY;
        float pos = (float)(k >> 1) + ((float)(k & 1) + 0.5f) * 0.5f;
        interp1d(x1 + pos * bin_w, W, s_xl[k], s_xh[k], s_wx0[k], s_wx1[k]);
    }
    __syncthreads();

    const float* feat = x + ((size_t)(b * C + c) * HW);
    float* op = out + ((size_t)(bn * C + c) * NBINS);

    #pragma unroll
    for (int oh = 0; oh < OUT_H; ++oh) {
        const int sy0 = oh * 2, sy1 = oh * 2 + 1;
        const float* r00 = feat + s_yl[sy0] * W;
        const float* r01 = feat + s_yh[sy0] * W;
        const float* r10 = feat + s_yl[sy1] * W;
        const float* r11 = feat + s_yh[sy1] * W;
        const float wy00 = s_wy0[sy0], wy01 = s_wy1[sy0];
        const float wy10 = s_wy0[sy1], wy11 = s_wy1[sy1];
        #pragma unroll
        for (int ow = 0; ow < OUT_W; ++ow) {
            float v = 0.0f;
            #pragma unroll
            for (int j = 0; j < 2; ++j) {
                const int sx = ow * 2 + j;
                const int xl = s_xl[sx], xh = s_xh[sx];
                const float wx0 = s_wx0[sx], wx1 = s_wx1[sx];
                v += wy00 * (wx0 * r00[xl] + wx1 * r00[xh])
                   + wy01 * (wx0 * r01[xl] + wx1 * r01[xh])
                   + wy10 * (wx0 * r10[xl] + wx1 * r10[xh])
                   + wy11 * (wx0 * r11[xl] + wx1 * r11[xh]);
            }
            op[oh * OUT_W + ow] = v * 0.25f;
        }
    }
}

extern "C" void kernel_launch(void* const* d_in, const int* in_sizes, int n_in,
                              void* d_out, int out_size, void* d_ws, size_t ws_size,
                              hipStream_t stream) {
    const float* x     = (const float*)d_in[0];
    const float* boxes = (const float*)d_in[1];
    float* out = (float*)d_out;

    const size_t need = (size_t)B * C * HW * sizeof(float);   // 134 MB
    if (ws_size >= need) {
        float* xt = (float*)d_ws;
        dim3 tgrid(HW / 32, C / 32, B);     // (512, 8, 8)
        dim3 tblock(32, 8);
        transpose_kernel<<<tgrid, tblock, 0, stream>>>(x, xt);
        dim3 rgrid(B * NBOX);
        dim3 rblock(64, 4);
        roi_align_nhwc_kernel<<<rgrid, rblock, 0, stream>>>(xt, boxes, out);
    } else {
        roi_align_nchw_kernel<<<B * NBOX, C, 0, stream>>>(x, boxes, out);
    }
}

// Round 3
// 211.327 us; speedup vs baseline: 2.3667x; 1.2062x over previous
//
#include <hip/hip_runtime.h>

// Problem constants (fixed by setup_inputs in the reference).
#define B 8
#define C 256
#define H 128
#define W 128
#define HW (H * W)
#define NBOX 64
#define OUT_H 6
#define OUT_W 6
#define NBINS (OUT_H * OUT_W)        // 36
#define ENT_PER_BOX 24               // 12 y-entries + 12 x-entries
#define TBL_N (B * NBOX * ENT_PER_BOX)   // 12288 entries

// torchvision bilinear_interpolate 1-D helper (aligned=True), matching
// reference _interp_1d exactly. Note: when at_edge, hi==lo==size-1 and
// frac==0, so storing only lo and reconstructing hi = min(lo+1, size-1)
// is exact (w1==0 whenever lo+1 would have been clamped).
__device__ __forceinline__ void interp1d(float coord, int size,
                                         int& lo, int& hi,
                                         float& w0, float& w1) {
    bool valid = (coord >= -1.0f) && (coord <= (float)size);
    float c = fmaxf(coord, 0.0f);
    int low0 = (int)floorf(c);
    bool at_edge = (low0 >= size - 1);
    lo = at_edge ? (size - 1) : low0;
    hi = at_edge ? (size - 1) : (low0 + 1);
    float frac = at_edge ? 0.0f : (c - (float)low0);
    w0 = valid ? (1.0f - frac) : 0.0f;
    w1 = valid ? frac : 0.0f;
}

// ---------------------------------------------------------------------------
// Precompute per-box sample tables into workspace.
// Entry idx = bn*24 + k; k<12 -> y-axis sample k, k>=12 -> x-axis sample k-12.
// t_lo[idx] in [0,127]; t_w[idx] = (w_lo, w_hi).
__global__ __launch_bounds__(256)
void table_kernel(const float* __restrict__ boxes,
                  int* __restrict__ t_lo, float2* __restrict__ t_w) {
    const int idx = blockIdx.x * 256 + threadIdx.x;
    if (idx >= TBL_N) return;
    const int bn = idx / ENT_PER_BOX;
    const int k = idx - bn * ENT_PER_BOX;
    const float* bx = boxes + bn * 4;
    const float x1 = bx[0] - 0.5f;    // SPATIAL_SCALE = 1, aligned=True
    const float y1 = bx[1] - 0.5f;
    const float x2 = bx[2] - 0.5f;
    const float y2 = bx[3] - 0.5f;
    const int kk = (k < 12) ? k : (k - 12);
    const float pos = (float)(kk >> 1) + ((float)(kk & 1) + 0.5f) * 0.5f;
    float coord;
    if (k < 12) coord = y1 + pos * ((y2 - y1) * (1.0f / OUT_H));
    else        coord = x1 + pos * ((x2 - x1) * (1.0f / OUT_W));
    int lo, hi; float w0, w1;
    interp1d(coord, 128, lo, hi, w0, w1);
    t_lo[idx] = lo;
    t_w[idx] = make_float2(w0, w1);
}

// ---------------------------------------------------------------------------
// One block per (b, c) plane. Stage the full 64 KB plane in LDS (read once,
// fully coalesced), then compute all 64 boxes x 36 bins for this channel.
// LDS = 64 KB -> 2 blocks/CU, so next block's staging overlaps compute.
__global__ __launch_bounds__(256)
void roi_plane_kernel(const float* __restrict__ x,
                      const int* __restrict__ t_lo,
                      const float2* __restrict__ t_w,
                      float* __restrict__ out) {
    __shared__ float plane[HW];           // 64 KB
    const int bid = blockIdx.x;           // 0 .. B*C-1
    const int b = bid >> 8;               // C == 256
    const int c = bid & 255;
    const int tid = threadIdx.x;

    // Stage plane: 4096 float4, 16 per thread, coalesced.
    const float4* src = (const float4*)(x + (size_t)bid * HW);
    float4* dst = (float4*)plane;
    #pragma unroll
    for (int i = 0; i < 16; ++i)
        dst[i * 256 + tid] = src[i * 256 + tid];
    __syncthreads();

    const int*    tl = t_lo + b * (NBOX * ENT_PER_BOX);
    const float2* tw = t_w  + b * (NBOX * ENT_PER_BOX);
    float* ob = out + ((size_t)b * NBOX * C + c) * NBINS;

    // 2304 outputs, 9 per thread.
    #pragma unroll
    for (int it = 0; it < 9; ++it) {
        const int k = it * 256 + tid;     // 0 .. 2303
        const int n = k / NBINS;
        const int bin = k - n * NBINS;
        const int oh = bin / OUT_W;
        const int ow = bin - oh * OUT_W;
        const int e = n * ENT_PER_BOX;

        float acc = 0.0f;
        #pragma unroll
        for (int i = 0; i < 2; ++i) {
            const int ye = e + oh * 2 + i;
            const int yl = tl[ye];
            const float2 wy = tw[ye];
            const int yh = min(yl + 1, H - 1);
            const float* r0 = plane + yl * W;
            const float* r1 = plane + yh * W;
            #pragma unroll
            for (int j = 0; j < 2; ++j) {
                const int xe = e + 12 + ow * 2 + j;
                const int xl = tl[xe];
                const float2 wx = tw[xe];
                const int xh = min(xl + 1, W - 1);
                acc += wy.x * (wx.x * r0[xl] + wx.y * r0[xh])
                     + wy.y * (wx.x * r1[xl] + wx.y * r1[xh]);
            }
        }
        ob[(size_t)n * (C * NBINS) + bin] = acc * 0.25f;
    }
}

// ---------------------------------------------------------------------------
// Fallback (round-1 style) if workspace is too small for the tables.
__global__ __launch_bounds__(256)
void roi_align_nchw_kernel(const float* __restrict__ x,
                           const float* __restrict__ boxes,
                           float* __restrict__ out) {
    const int bn = blockIdx.x;
    const int b = bn / NBOX;
    const int c = threadIdx.x;

    __shared__ int   s_yl[12], s_xl[12];
    __shared__ float s_wy0[12], s_wy1[12], s_wx0[12], s_wx1[12];

    const float* bx = boxes + (bn * 4);
    const float x1 = bx[0] - 0.5f, y1 = bx[1] - 0.5f;
    const float x2 = bx[2] - 0.5f, y2 = bx[3] - 0.5f;
    const float bin_h = (y2 - y1) * (1.0f / OUT_H);
    const float bin_w = (x2 - x1) * (1.0f / OUT_W);

    if (threadIdx.x < 12) {
        int k = threadIdx.x;
        float pos = (float)(k >> 1) + ((float)(k & 1) + 0.5f) * 0.5f;
        int hi;
        interp1d(y1 + pos * bin_h, H, s_yl[k], hi, s_wy0[k], s_wy1[k]);
    } else if (threadIdx.x < 24) {
        int k = threadIdx.x - 12;
        float pos = (float)(k >> 1) + ((float)(k & 1) + 0.5f) * 0.5f;
        int hi;
        interp1d(x1 + pos * bin_w, W, s_xl[k], hi, s_wx0[k], s_wx1[k]);
    }
    __syncthreads();

    const float* feat = x + ((size_t)(b * C + c) * HW);
    float* op = out + ((size_t)(bn * C + c) * NBINS);

    for (int oh = 0; oh < OUT_H; ++oh) {
        for (int ow = 0; ow < OUT_W; ++ow) {
            float v = 0.0f;
            for (int i = 0; i < 2; ++i) {
                const int sy = oh * 2 + i;
                const int yl = s_yl[sy], yh = min(yl + 1, H - 1);
                const float wy0 = s_wy0[sy], wy1 = s_wy1[sy];
                for (int j = 0; j < 2; ++j) {
                    const int sx = ow * 2 + j;
                    const int xl = s_xl[sx], xh = min(xl + 1, W - 1);
                    v += wy0 * (s_wx0[sx] * feat[yl * W + xl] + s_wx1[sx] * feat[yl * W + xh])
                       + wy1 * (s_wx0[sx] * feat[yh * W + xl] + s_wx1[sx] * feat[yh * W + xh]);
                }
            }
            op[oh * OUT_W + ow] = v * 0.25f;
        }
    }
}

extern "C" void kernel_launch(void* const* d_in, const int* in_sizes, int n_in,
                              void* d_out, int out_size, void* d_ws, size_t ws_size,
                              hipStream_t stream) {
    const float* x     = (const float*)d_in[0];
    const float* boxes = (const float*)d_in[1];
    float* out = (float*)d_out;

    const size_t tbl_bytes = (size_t)TBL_N * sizeof(int)        // t_lo
                           + (size_t)TBL_N * sizeof(float2);    // t_w
    if (ws_size >= tbl_bytes) {
        int* t_lo = (int*)d_ws;
        float2* t_w = (float2*)((char*)d_ws + (size_t)TBL_N * sizeof(int));
        table_kernel<<<(TBL_N + 255) / 256, 256, 0, stream>>>(boxes, t_lo, t_w);
        roi_plane_kernel<<<B * C, 256, 0, stream>>>(x, t_lo, t_w, out);
    } else {
        roi_align_nchw_kernel<<<B * NBOX, C, 0, stream>>>(x, boxes, out);
    }
}

// Round 4
// 205.423 us; speedup vs baseline: 2.4347x; 1.0287x over previous
//
#include <hip/hip_runtime.h>

// Problem constants (fixed by setup_inputs in the reference).
#define B 8
#define C 256
#define H 128
#define W 128
#define HW (H * W)
#define NBOX 64
#define OUT_H 6
#define OUT_W 6
#define NBINS (OUT_H * OUT_W)        // 36
#define ENT_PER_BOX 24               // 12 y-entries + 12 x-entries
#define TBL_N (B * NBOX * ENT_PER_BOX)   // 12288 entries
#define PITCH 132                    // LDS row pitch: 128 + 4 (bank de-alias, 16B-aligned)

// torchvision bilinear_interpolate 1-D helper (aligned=True), matching
// reference _interp_1d exactly. Key fact exploited downstream: whenever
// hi != lo+1 in the reference (at_edge), w1 == 0 — so always reading lo+1
// (into a zeroed pad) and weighting by w1 is exact.
__device__ __forceinline__ void interp1d(float coord, int size,
                                         int& lo, float& w0, float& w1) {
    bool valid = (coord >= -1.0f) && (coord <= (float)size);
    float c = fmaxf(coord, 0.0f);
    int low0 = (int)floorf(c);
    bool at_edge = (low0 >= size - 1);
    lo = at_edge ? (size - 1) : low0;
    float frac = at_edge ? 0.0f : (c - (float)low0);
    w0 = valid ? (1.0f - frac) : 0.0f;
    w1 = valid ? frac : 0.0f;
}

// ---------------------------------------------------------------------------
// Precompute per-box sample tables into workspace as float4 {w0, w1, lo, 0}.
// Entry idx = bn*24 + k; k<12 -> y-axis sample k, k>=12 -> x-axis sample k-12.
__global__ __launch_bounds__(256)
void table_kernel(const float* __restrict__ boxes, float4* __restrict__ tbl) {
    const int idx = blockIdx.x * 256 + threadIdx.x;
    if (idx >= TBL_N) return;
    const int bn = idx / ENT_PER_BOX;
    const int k = idx - bn * ENT_PER_BOX;
    const float* bx = boxes + bn * 4;
    const float x1 = bx[0] - 0.5f;    // SPATIAL_SCALE = 1, aligned=True
    const float y1 = bx[1] - 0.5f;
    const float x2 = bx[2] - 0.5f;
    const float y2 = bx[3] - 0.5f;
    const int kk = (k < 12) ? k : (k - 12);
    const float pos = (float)(kk >> 1) + ((float)(kk & 1) + 0.5f) * 0.5f;
    float coord;
    if (k < 12) coord = y1 + pos * ((y2 - y1) * (1.0f / OUT_H));
    else        coord = x1 + pos * ((x2 - x1) * (1.0f / OUT_W));
    int lo; float w0, w1;
    interp1d(coord, 128, lo, w0, w1);
    tbl[idx] = make_float4(w0, w1, (float)lo, 0.0f);
}

// ---------------------------------------------------------------------------
// One block per (b, c) plane. Stage the full plane in LDS with a padded
// pitch (bank de-aliasing: 128 % 32 == 0 made every row hit identical
// banks; pitch 132 gives bank = (4y+x) % 32). Zeroed pad column + pad row
// let every bilinear tap read (lo, lo+1) unconditionally -> ds_read2_b32.
__global__ __launch_bounds__(256)
void roi_plane_kernel(const float* __restrict__ x,
                      const float4* __restrict__ tbl,
                      float* __restrict__ out) {
    __shared__ float plane[(H + 1) * PITCH];   // 129*132*4 = 68112 B
    const int bid = blockIdx.x;                // 0 .. B*C-1
    const int b = bid >> 8;                    // C == 256
    const int c = bid & 255;
    const int tid = threadIdx.x;

    // Stage plane: 4096 float4 (32 per row), 16 per thread, coalesced reads.
    const float4* src = (const float4*)(x + (size_t)bid * HW);
    #pragma unroll
    for (int i = 0; i < 16; ++i) {
        const int m = i * 256 + tid;           // chunk id 0..4095
        const int row = m >> 5;
        const int col = (m & 31) << 2;
        *(float4*)&plane[row * PITCH + col] = src[m];
    }
    // Zero the pads (so "always read lo+1" taps multiply 0-weight by 0.0,
    // never by garbage): 4-float pad per row + the whole extra row 128.
    const float4 z4 = make_float4(0.f, 0.f, 0.f, 0.f);
    if (tid < H) *(float4*)&plane[tid * PITCH + W] = z4;
    if (tid < PITCH / 4) *(float4*)&plane[H * PITCH + tid * 4] = z4;
    __syncthreads();

    const float4* tb = tbl + b * (NBOX * ENT_PER_BOX);
    float* ob = out + ((size_t)b * NBOX * C + c) * NBINS;

    // 2304 outputs (64 boxes x 36 bins), 9 per thread.
    #pragma unroll
    for (int it = 0; it < 9; ++it) {
        const int k = it * 256 + tid;          // 0 .. 2303
        const int n = k / NBINS;
        const int bin = k - n * NBINS;
        const int oh = bin / OUT_W;
        const int ow = bin - oh * OUT_W;
        const int e = n * ENT_PER_BOX;

        const float4 tx0 = tb[e + 12 + ow * 2 + 0];
        const float4 tx1 = tb[e + 12 + ow * 2 + 1];
        const int xl0 = (int)tx0.z, xl1 = (int)tx1.z;

        float acc = 0.0f;
        #pragma unroll
        for (int i = 0; i < 2; ++i) {
            const float4 ty = tb[e + oh * 2 + i];
            const int yl = (int)ty.z;
            const float* r0 = plane + yl * PITCH;
            const float* r1 = r0 + PITCH;      // row yl+1 (pad row if yl==127; ty.y==0 then)
            // sample j=0
            acc += ty.x * (tx0.x * r0[xl0] + tx0.y * r0[xl0 + 1])
                 + ty.y * (tx0.x * r1[xl0] + tx0.y * r1[xl0 + 1]);
            // sample j=1
            acc += ty.x * (tx1.x * r0[xl1] + tx1.y * r0[xl1 + 1])
                 + ty.y * (tx1.x * r1[xl1] + tx1.y * r1[xl1 + 1]);
        }
        ob[(size_t)n * (C * NBINS) + bin] = acc * 0.25f;
    }
}

// ---------------------------------------------------------------------------
// Fallback (round-1 style) if workspace is too small for the tables.
__global__ __launch_bounds__(256)
void roi_align_nchw_kernel(const float* __restrict__ x,
                           const float* __restrict__ boxes,
                           float* __restrict__ out) {
    const int bn = blockIdx.x;
    const int b = bn / NBOX;
    const int c = threadIdx.x;

    __shared__ int   s_yl[12], s_xl[12];
    __shared__ float s_wy0[12], s_wy1[12], s_wx0[12], s_wx1[12];

    const float* bx = boxes + (bn * 4);
    const float x1 = bx[0] - 0.5f, y1 = bx[1] - 0.5f;
    const float x2 = bx[2] - 0.5f, y2 = bx[3] - 0.5f;
    const float bin_h = (y2 - y1) * (1.0f / OUT_H);
    const float bin_w = (x2 - x1) * (1.0f / OUT_W);

    if (threadIdx.x < 12) {
        int k = threadIdx.x;
        float pos = (float)(k >> 1) + ((float)(k & 1) + 0.5f) * 0.5f;
        interp1d(y1 + pos * bin_h, H, s_yl[k], s_wy0[k], s_wy1[k]);
    } else if (threadIdx.x < 24) {
        int k = threadIdx.x - 12;
        float pos = (float)(k >> 1) + ((float)(k & 1) + 0.5f) * 0.5f;
        interp1d(x1 + pos * bin_w, W, s_xl[k], s_wx0[k], s_wx1[k]);
    }
    __syncthreads();

    const float* feat = x + ((size_t)(b * C + c) * HW);
    float* op = out + ((size_t)(bn * C + c) * NBINS);

    for (int oh = 0; oh < OUT_H; ++oh) {
        for (int ow = 0; ow < OUT_W; ++ow) {
            float v = 0.0f;
            for (int i = 0; i < 2; ++i) {
                const int sy = oh * 2 + i;
                const int yl = s_yl[sy], yh = min(yl + 1, H - 1);
                const float wy0 = s_wy0[sy], wy1 = s_wy1[sy];
                for (int j = 0; j < 2; ++j) {
                    const int sx = ow * 2 + j;
                    const int xl = s_xl[sx], xh = min(xl + 1, W - 1);
                    v += wy0 * (s_wx0[sx] * feat[yl * W + xl] + s_wx1[sx] * feat[yl * W + xh])
                       + wy1 * (s_wx0[sx] * feat[yh * W + xl] + s_wx1[sx] * feat[yh * W + xh]);
                }
            }
            op[oh * OUT_W + ow] = v * 0.25f;
        }
    }
}

extern "C" void kernel_launch(void* const* d_in, const int* in_sizes, int n_in,
                              void* d_out, int out_size, void* d_ws, size_t ws_size,
                              hipStream_t stream) {
    const float* x     = (const float*)d_in[0];
    const float* boxes = (const float*)d_in[1];
    float* out = (float*)d_out;

    const size_t tbl_bytes = (size_t)TBL_N * sizeof(float4);   // 196 KB
    if (ws_size >= tbl_bytes) {
        float4* tbl = (float4*)d_ws;
        table_kernel<<<(TBL_N + 255) / 256, 256, 0, stream>>>(boxes, tbl);
        roi_plane_kernel<<<B * C, 256, 0, stream>>>(x, tbl, out);
    } else {
        roi_align_nchw_kernel<<<B * NBOX, C, 0, stream>>>(x, boxes, out);
    }
}

// Round 5
// 201.281 us; speedup vs baseline: 2.4848x; 1.0206x over previous
//
#include <hip/hip_runtime.h>

// Problem constants (fixed by setup_inputs in the reference).
#define B 8
#define C 256
#define H 128
#define W 128
#define HW (H * W)
#define NBOX 64
#define OUT_H 6
#define OUT_W 6
#define NBINS (OUT_H * OUT_W)        // 36
#define ENT_PER_BOX 24               // 12 y-entries + 12 x-entries
#define TBL_N (B * NBOX * ENT_PER_BOX)   // 12288 entries
#define PITCH 132                    // LDS row pitch: 128 + 4 (bank de-alias, 16B-aligned)
#define NOUT (NBOX * NBINS)          // 2304 outputs per (b,c) plane

// torchvision bilinear_interpolate 1-D helper (aligned=True), matching
// reference _interp_1d exactly. Key fact exploited downstream: whenever
// hi != lo+1 in the reference (at_edge), w1 == 0 — so always reading lo+1
// (into a zeroed pad) and weighting by w1 is exact.
__device__ __forceinline__ void interp1d(float coord, int size,
                                         int& lo, float& w0, float& w1) {
    bool valid = (coord >= -1.0f) && (coord <= (float)size);
    float c = fmaxf(coord, 0.0f);
    int low0 = (int)floorf(c);
    bool at_edge = (low0 >= size - 1);
    lo = at_edge ? (size - 1) : low0;
    float frac = at_edge ? 0.0f : (c - (float)low0);
    w0 = valid ? (1.0f - frac) : 0.0f;
    w1 = valid ? frac : 0.0f;
}

// ---------------------------------------------------------------------------
// Precompute per-box sample tables into workspace as float4 {w0, w1, lo, 0}.
// Entry idx = bn*24 + k; k<12 -> y-axis sample k, k>=12 -> x-axis sample k-12.
__global__ __launch_bounds__(256)
void table_kernel(const float* __restrict__ boxes, float4* __restrict__ tbl) {
    const int idx = blockIdx.x * 256 + threadIdx.x;
    if (idx >= TBL_N) return;
    const int bn = idx / ENT_PER_BOX;
    const int k = idx - bn * ENT_PER_BOX;
    const float* bx = boxes + bn * 4;
    const float x1 = bx[0] - 0.5f;    // SPATIAL_SCALE = 1, aligned=True
    const float y1 = bx[1] - 0.5f;
    const float x2 = bx[2] - 0.5f;
    const float y2 = bx[3] - 0.5f;
    const int kk = (k < 12) ? k : (k - 12);
    const float pos = (float)(kk >> 1) + ((float)(kk & 1) + 0.5f) * 0.5f;
    float coord;
    if (k < 12) coord = y1 + pos * ((y2 - y1) * (1.0f / OUT_H));
    else        coord = x1 + pos * ((x2 - x1) * (1.0f / OUT_W));
    int lo; float w0, w1;
    interp1d(coord, 128, lo, w0, w1);
    tbl[idx] = make_float4(w0, w1, (float)lo, 0.0f);
}

// ---------------------------------------------------------------------------
// One block per (b, c) plane, 1024 threads (16 waves). LDS = 68 KB -> 2
// blocks/CU = 32 waves/CU: enough TLP to hide HBM latency in the staging
// phase (R4's 256-thread version was latency-bound at 8 waves/CU).
// Padded pitch de-aliases LDS banks; zeroed pad column/row let every
// bilinear tap read (lo, lo+1) unconditionally.
__global__ __launch_bounds__(1024)
void roi_plane_kernel(const float* __restrict__ x,
                      const float4* __restrict__ tbl,
                      float* __restrict__ out) {
    __shared__ float plane[(H + 1) * PITCH];   // 129*132*4 = 68112 B
    const int bid = blockIdx.x;                // 0 .. B*C-1
    const int b = bid >> 8;                    // C == 256
    const int c = bid & 255;
    const int tid = threadIdx.x;               // 0 .. 1023

    // Stage plane: 4096 float4 (32 per row), 4 per thread, coalesced reads.
    const float4* src = (const float4*)(x + (size_t)bid * HW);
    #pragma unroll
    for (int i = 0; i < 4; ++i) {
        const int m = i * 1024 + tid;          // chunk id 0..4095
        const int row = m >> 5;
        const int col = (m & 31) << 2;
        *(float4*)&plane[row * PITCH + col] = src[m];
    }
    // Zero the pads (so "always read lo+1" taps multiply 0-weight by 0.0,
    // never by garbage): 4-float pad per row + the whole extra row 128.
    const float4 z4 = make_float4(0.f, 0.f, 0.f, 0.f);
    if (tid < H) *(float4*)&plane[tid * PITCH + W] = z4;
    else if (tid >= 1024 - PITCH / 4)
        *(float4*)&plane[H * PITCH + (tid - (1024 - PITCH / 4)) * 4] = z4;
    __syncthreads();

    const float4* tb = tbl + b * (NBOX * ENT_PER_BOX);
    float* ob = out + ((size_t)b * NBOX * C + c) * NBINS;

    // 2304 outputs (64 boxes x 36 bins), <=3 per thread.
    #pragma unroll
    for (int it = 0; it < 3; ++it) {
        const int k = it * 1024 + tid;         // 0 .. 3071
        if (k < NOUT) {
            const int n = k / NBINS;
            const int bin = k - n * NBINS;
            const int oh = bin / OUT_W;
            const int ow = bin - oh * OUT_W;
            const int e = n * ENT_PER_BOX;

            const float4 tx0 = tb[e + 12 + ow * 2 + 0];
            const float4 tx1 = tb[e + 12 + ow * 2 + 1];
            const int xl0 = (int)tx0.z, xl1 = (int)tx1.z;

            float acc = 0.0f;
            #pragma unroll
            for (int i = 0; i < 2; ++i) {
                const float4 ty = tb[e + oh * 2 + i];
                const int yl = (int)ty.z;
                const float* r0 = plane + yl * PITCH;
                const float* r1 = r0 + PITCH;  // row yl+1 (pad row if yl==127; ty.y==0 then)
                acc += ty.x * (tx0.x * r0[xl0] + tx0.y * r0[xl0 + 1])
                     + ty.y * (tx0.x * r1[xl0] + tx0.y * r1[xl0 + 1]);
                acc += ty.x * (tx1.x * r0[xl1] + tx1.y * r0[xl1 + 1])
                     + ty.y * (tx1.x * r1[xl1] + tx1.y * r1[xl1 + 1]);
            }
            ob[(size_t)n * (C * NBINS) + bin] = acc * 0.25f;
        }
    }
}

// ---------------------------------------------------------------------------
// Fallback (round-1 style) if workspace is too small for the tables.
__global__ __launch_bounds__(256)
void roi_align_nchw_kernel(const float* __restrict__ x,
                           const float* __restrict__ boxes,
                           float* __restrict__ out) {
    const int bn = blockIdx.x;
    const int b = bn / NBOX;
    const int c = threadIdx.x;

    __shared__ int   s_yl[12], s_xl[12];
    __shared__ float s_wy0[12], s_wy1[12], s_wx0[12], s_wx1[12];

    const float* bx = boxes + (bn * 4);
    const float x1 = bx[0] - 0.5f, y1 = bx[1] - 0.5f;
    const float x2 = bx[2] - 0.5f, y2 = bx[3] - 0.5f;
    const float bin_h = (y2 - y1) * (1.0f / OUT_H);
    const float bin_w = (x2 - x1) * (1.0f / OUT_W);

    if (threadIdx.x < 12) {
        int k = threadIdx.x;
        float pos = (float)(k >> 1) + ((float)(k & 1) + 0.5f) * 0.5f;
        interp1d(y1 + pos * bin_h, H, s_yl[k], s_wy0[k], s_wy1[k]);
    } else if (threadIdx.x < 24) {
        int k = threadIdx.x - 12;
        float pos = (float)(k >> 1) + ((float)(k & 1) + 0.5f) * 0.5f;
        interp1d(x1 + pos * bin_w, W, s_xl[k], s_wx0[k], s_wx1[k]);
    }
    __syncthreads();

    const float* feat = x + ((size_t)(b * C + c) * HW);
    float* op = out + ((size_t)(bn * C + c) * NBINS);

    for (int oh = 0; oh < OUT_H; ++oh) {
        for (int ow = 0; ow < OUT_W; ++ow) {
            float v = 0.0f;
            for (int i = 0; i < 2; ++i) {
                const int sy = oh * 2 + i;
                const int yl = s_yl[sy], yh = min(yl + 1, H - 1);
                const float wy0 = s_wy0[sy], wy1 = s_wy1[sy];
                for (int j = 0; j < 2; ++j) {
                    const int sx = ow * 2 + j;
                    const int xl = s_xl[sx], xh = min(xl + 1, W - 1);
                    v += wy0 * (s_wx0[sx] * feat[yl * W + xl] + s_wx1[sx] * feat[yl * W + xh])
                       + wy1 * (s_wx0[sx] * feat[yh * W + xl] + s_wx1[sx] * feat[yh * W + xh]);
                }
            }
            op[oh * OUT_W + ow] = v * 0.25f;
        }
    }
}

extern "C" void kernel_launch(void* const* d_in, const int* in_sizes, int n_in,
                              void* d_out, int out_size, void* d_ws, size_t ws_size,
                              hipStream_t stream) {
    const float* x     = (const float*)d_in[0];
    const float* boxes = (const float*)d_in[1];
    float* out = (float*)d_out;

    const size_t tbl_bytes = (size_t)TBL_N * sizeof(float4);   // 196 KB
    if (ws_size >= tbl_bytes) {
        float4* tbl = (float4*)d_ws;
        table_kernel<<<(TBL_N + 255) / 256, 256, 0, stream>>>(boxes, tbl);
        roi_plane_kernel<<<B * C, 1024, 0, stream>>>(x, tbl, out);
    } else {
        roi_align_nchw_kernel<<<B * NBOX, C, 0, stream>>>(x, boxes, out);
    }
}

// Round 6
// 200.976 us; speedup vs baseline: 2.4886x; 1.0015x over previous
//
#include <hip/hip_runtime.h>

// Problem constants (fixed by setup_inputs in the reference).
#define B 8
#define C 256
#define H 128
#define W 128
#define HW (H * W)
#define NBOX 64
#define OUT_H 6
#define OUT_W 6
#define NBINS (OUT_H * OUT_W)        // 36
#define ENT_PER_BOX 24               // 12 y-entries + 12 x-entries
#define TBL_N (B * NBOX * ENT_PER_BOX)   // 12288 entries
#define PITCH 132                    // LDS row pitch: 128 + 4 (bank de-alias, 16B-aligned)
#define NOUT (NBOX * NBINS)          // 2304 outputs per (b,c) plane

// torchvision bilinear_interpolate 1-D helper (aligned=True), matching
// reference _interp_1d exactly. Key fact exploited downstream: whenever
// hi != lo+1 in the reference (at_edge), w1 == 0 — so always reading lo+1
// (into a zeroed pad) and weighting by w1 is exact.
__device__ __forceinline__ void interp1d(float coord, int size,
                                         int& lo, float& w0, float& w1) {
    bool valid = (coord >= -1.0f) && (coord <= (float)size);
    float c = fmaxf(coord, 0.0f);
    int low0 = (int)floorf(c);
    bool at_edge = (low0 >= size - 1);
    lo = at_edge ? (size - 1) : low0;
    float frac = at_edge ? 0.0f : (c - (float)low0);
    w0 = valid ? (1.0f - frac) : 0.0f;
    w1 = valid ? frac : 0.0f;
}

// ---------------------------------------------------------------------------
// Precompute per-box sample tables into workspace as float4 {w0, w1, lo, 0}.
// Entry idx = bn*24 + k; k<12 -> y-axis sample k, k>=12 -> x-axis sample k-12.
__global__ __launch_bounds__(256)
void table_kernel(const float* __restrict__ boxes, float4* __restrict__ tbl) {
    const int idx = blockIdx.x * 256 + threadIdx.x;
    if (idx >= TBL_N) return;
    const int bn = idx / ENT_PER_BOX;
    const int k = idx - bn * ENT_PER_BOX;
    const float* bx = boxes + bn * 4;
    const float x1 = bx[0] - 0.5f;    // SPATIAL_SCALE = 1, aligned=True
    const float y1 = bx[1] - 0.5f;
    const float x2 = bx[2] - 0.5f;
    const float y2 = bx[3] - 0.5f;
    const int kk = (k < 12) ? k : (k - 12);
    const float pos = (float)(kk >> 1) + ((float)(kk & 1) + 0.5f) * 0.5f;
    float coord;
    if (k < 12) coord = y1 + pos * ((y2 - y1) * (1.0f / OUT_H));
    else        coord = x1 + pos * ((x2 - x1) * (1.0f / OUT_W));
    int lo; float w0, w1;
    interp1d(coord, 128, lo, w0, w1);
    tbl[idx] = make_float4(w0, w1, (float)lo, 0.0f);
}

// ---------------------------------------------------------------------------
// One block per (b, c) plane, 1024 threads (16 waves).
// __launch_bounds__(1024, 8): 8 waves/EU -> 2 blocks/CU (LDS 2x68 KB = 136 KB
// fits in 160 KB). Two resident blocks give stage/compute overlap across
// blocks AND 32 waves/CU of TLP — R4 had overlap at 8 waves, R5 had 16 waves
// with no overlap (VGPR>64 -> 1 block/CU); this forces both.
// Padded pitch de-aliases LDS banks; zeroed pad column/row let every
// bilinear tap read (lo, lo+1) unconditionally.
__global__ __launch_bounds__(1024, 8)
void roi_plane_kernel(const float* __restrict__ x,
                      const float4* __restrict__ tbl,
                      float* __restrict__ out) {
    __shared__ float plane[(H + 1) * PITCH];   // 129*132*4 = 68112 B
    const int bid = blockIdx.x;                // 0 .. B*C-1
    const int b = bid >> 8;                    // C == 256
    const int c = bid & 255;
    const int tid = threadIdx.x;               // 0 .. 1023

    // Stage plane: 4096 float4 (32 per row), 4 per thread, coalesced reads.
    const float4* src = (const float4*)(x + (size_t)bid * HW);
    #pragma unroll
    for (int i = 0; i < 4; ++i) {
        const int m = i * 1024 + tid;          // chunk id 0..4095
        const int row = m >> 5;
        const int col = (m & 31) << 2;
        *(float4*)&plane[row * PITCH + col] = src[m];
    }
    // Zero the pads (so "always read lo+1" taps multiply 0-weight by 0.0,
    // never by garbage): 4-float pad per row + the whole extra row 128.
    const float4 z4 = make_float4(0.f, 0.f, 0.f, 0.f);
    if (tid < H) *(float4*)&plane[tid * PITCH + W] = z4;
    else if (tid >= 1024 - PITCH / 4)
        *(float4*)&plane[H * PITCH + (tid - (1024 - PITCH / 4)) * 4] = z4;
    __syncthreads();

    const float4* tb = tbl + b * (NBOX * ENT_PER_BOX);
    float* ob = out + ((size_t)b * NBOX * C + c) * NBINS;

    // 2304 outputs (64 boxes x 36 bins), <=3 per thread.
    // unroll 1: keep live-register count low so the 64-VGPR budget from
    // __launch_bounds__(1024,8) holds without spilling.
    #pragma unroll 1
    for (int it = 0; it < 3; ++it) {
        const int k = it * 1024 + tid;         // 0 .. 3071
        if (k < NOUT) {
            const int n = k / NBINS;
            const int bin = k - n * NBINS;
            const int oh = bin / OUT_W;
            const int ow = bin - oh * OUT_W;
            const int e = n * ENT_PER_BOX;

            const float4 tx0 = tb[e + 12 + ow * 2 + 0];
            const float4 tx1 = tb[e + 12 + ow * 2 + 1];
            const int xl0 = (int)tx0.z, xl1 = (int)tx1.z;

            float acc = 0.0f;
            #pragma unroll
            for (int i = 0; i < 2; ++i) {
                const float4 ty = tb[e + oh * 2 + i];
                const int yl = (int)ty.z;
                const float* r0 = plane + yl * PITCH;
                const float* r1 = r0 + PITCH;  // row yl+1 (pad row if yl==127; ty.y==0 then)
                acc += ty.x * (tx0.x * r0[xl0] + tx0.y * r0[xl0 + 1])
                     + ty.y * (tx0.x * r1[xl0] + tx0.y * r1[xl0 + 1]);
                acc += ty.x * (tx1.x * r0[xl1] + tx1.y * r0[xl1 + 1])
                     + ty.y * (tx1.x * r1[xl1] + tx1.y * r1[xl1 + 1]);
            }
            ob[(size_t)n * (C * NBINS) + bin] = acc * 0.25f;
        }
    }
}

// ---------------------------------------------------------------------------
// Fallback (round-1 style) if workspace is too small for the tables.
__global__ __launch_bounds__(256)
void roi_align_nchw_kernel(const float* __restrict__ x,
                           const float* __restrict__ boxes,
                           float* __restrict__ out) {
    const int bn = blockIdx.x;
    const int b = bn / NBOX;
    const int c = threadIdx.x;

    __shared__ int   s_yl[12], s_xl[12];
    __shared__ float s_wy0[12], s_wy1[12], s_wx0[12], s_wx1[12];

    const float* bx = boxes + (bn * 4);
    const float x1 = bx[0] - 0.5f, y1 = bx[1] - 0.5f;
    const float x2 = bx[2] - 0.5f, y2 = bx[3] - 0.5f;
    const float bin_h = (y2 - y1) * (1.0f / OUT_H);
    const float bin_w = (x2 - x1) * (1.0f / OUT_W);

    if (threadIdx.x < 12) {
        int k = threadIdx.x;
        float pos = (float)(k >> 1) + ((float)(k & 1) + 0.5f) * 0.5f;
        interp1d(y1 + pos * bin_h, H, s_yl[k], s_wy0[k], s_wy1[k]);
    } else if (threadIdx.x < 24) {
        int k = threadIdx.x - 12;
        float pos = (float)(k >> 1) + ((float)(k & 1) + 0.5f) * 0.5f;
        interp1d(x1 + pos * bin_w, W, s_xl[k], s_wx0[k], s_wx1[k]);
    }
    __syncthreads();

    const float* feat = x + ((size_t)(b * C + c) * HW);
    float* op = out + ((size_t)(bn * C + c) * NBINS);

    for (int oh = 0; oh < OUT_H; ++oh) {
        for (int ow = 0; ow < OUT_W; ++ow) {
            float v = 0.0f;
            for (int i = 0; i < 2; ++i) {
                const int sy = oh * 2 + i;
                const int yl = s_yl[sy], yh = min(yl + 1, H - 1);
                const float wy0 = s_wy0[sy], wy1 = s_wy1[sy];
                for (int j = 0; j < 2; ++j) {
                    const int sx = ow * 2 + j;
                    const int xl = s_xl[sx], xh = min(xl + 1, W - 1);
                    v += wy0 * (s_wx0[sx] * feat[yl * W + xl] + s_wx1[sx] * feat[yl * W + xh])
                       + wy1 * (s_wx0[sx] * feat[yh * W + xl] + s_wx1[sx] * feat[yh * W + xh]);
                }
            }
            op[oh * OUT_W + ow] = v * 0.25f;
        }
    }
}

extern "C" void kernel_launch(void* const* d_in, const int* in_sizes, int n_in,
                              void* d_out, int out_size, void* d_ws, size_t ws_size,
                              hipStream_t stream) {
    const float* x     = (const float*)d_in[0];
    const float* boxes = (const float*)d_in[1];
    float* out = (float*)d_out;

    const size_t tbl_bytes = (size_t)TBL_N * sizeof(float4);   // 196 KB
    if (ws_size >= tbl_bytes) {
        float4* tbl = (float4*)d_ws;
        table_kernel<<<(TBL_N + 255) / 256, 256, 0, stream>>>(boxes, tbl);
        roi_plane_kernel<<<B * C, 1024, 0, stream>>>(x, tbl, out);
    } else {
        roi_align_nchw_kernel<<<B * NBOX, C, 0, stream>>>(x, boxes, out);
    }
}

// Round 7
// 200.506 us; speedup vs baseline: 2.4944x; 1.0023x over previous
//
#include <hip/hip_runtime.h>

// Problem constants (fixed by setup_inputs in the reference).
#define B 8
#define C 256
#define H 128
#define W 128
#define HW (H * W)
#define NBOX 64
#define OUT_H 6
#define OUT_W 6
#define NBINS (OUT_H * OUT_W)        // 36
#define ENT_PER_BOX 24               // 12 y-entries + 12 x-entries
#define TBL_PER_B (NBOX * ENT_PER_BOX)   // 1536 entries per batch image
#define PITCH 132                    // LDS row pitch: 128 + 4 (bank de-alias, 16B-aligned)
#define PLANE_ELEMS ((H + 1) * PITCH)    // 17028 floats = 68112 B
#define NOUT (NBOX * NBINS)          // 2304 outputs per (b,c) plane
#define PLANES_PER_BLOCK 8
#define NBLK (B * C / PLANES_PER_BLOCK)  // 256 blocks = 1 per CU

// torchvision bilinear_interpolate 1-D helper (aligned=True), matching
// reference _interp_1d exactly. Whenever hi != lo+1 in the reference
// (at_edge), w1 == 0 — so always reading lo+1 (into a zeroed pad) and
// weighting by w1 is exact.
__device__ __forceinline__ void interp1d(float coord, int size,
                                         int& lo, float& w0, float& w1) {
    bool valid = (coord >= -1.0f) && (coord <= (float)size);
    float c = fmaxf(coord, 0.0f);
    int low0 = (int)floorf(c);
    bool at_edge = (low0 >= size - 1);
    lo = at_edge ? (size - 1) : low0;
    float frac = at_edge ? 0.0f : (c - (float)low0);
    w0 = valid ? (1.0f - frac) : 0.0f;
    w1 = valid ? frac : 0.0f;
}

// ---------------------------------------------------------------------------
// Persistent double-buffered kernel. 256 blocks x 1024 threads (16 waves),
// exactly 1 block/CU (LDS 157 KB). Each block owns 8 channel-planes of one
// batch image. Per plane: next plane's loads are issued BEFORE computing the
// current plane from LDS, so HBM latency hides under compute; the only
// serialization is ds_write + barrier. The per-batch sample table (1536
// float4) is computed in-kernel and kept in LDS — the hot loop has zero
// global loads.
__global__ __launch_bounds__(1024, 4)
void roi_persist_kernel(const float* __restrict__ x,
                        const float* __restrict__ boxes,
                        float* __restrict__ out) {
    __shared__ float buf0[PLANE_ELEMS];          // 68112 B
    __shared__ float buf1[PLANE_ELEMS];          // 68112 B
    __shared__ float4 stab[TBL_PER_B];           // 24576 B  (total 160800 <= 160 KiB)

    const int blk = blockIdx.x;                  // 0..255
    const int b = blk >> 5;                      // 32 blocks per batch image
    const int c0 = (blk & 31) * PLANES_PER_BLOCK;
    const int tid = threadIdx.x;                 // 0..1023

    // ---- build this batch's sample table in LDS (entry i = n*24 + k) ----
    #pragma unroll
    for (int i = tid; i < TBL_PER_B; i += 1024) {
        const int n = i / ENT_PER_BOX;
        const int k = i - n * ENT_PER_BOX;
        const float* bx = boxes + ((size_t)(b * NBOX + n)) * 4;
        const float x1 = bx[0] - 0.5f;           // SPATIAL_SCALE=1, aligned=True
        const float y1 = bx[1] - 0.5f;
        const float x2 = bx[2] - 0.5f;
        const float y2 = bx[3] - 0.5f;
        const int kk = (k < 12) ? k : (k - 12);
        const float pos = (float)(kk >> 1) + ((float)(kk & 1) + 0.5f) * 0.5f;
        float coord;
        if (k < 12) coord = y1 + pos * ((y2 - y1) * (1.0f / OUT_H));
        else        coord = x1 + pos * ((x2 - x1) * (1.0f / OUT_W));
        int lo; float w0, w1;
        interp1d(coord, 128, lo, w0, w1);
        stab[i] = make_float4(w0, w1, (float)lo, 0.0f);
    }

    // ---- zero the pads of BOTH buffers once (staging never touches them) --
    // pad column: rows 0..127, floats [W..W+4) ; pad row: row 128 entirely.
    const float4 z4 = make_float4(0.f, 0.f, 0.f, 0.f);
    if (tid < H) {
        *(float4*)&buf0[tid * PITCH + W] = z4;
        *(float4*)&buf1[tid * PITCH + W] = z4;
    } else if (tid >= 1024 - PITCH / 4) {
        const int j = (tid - (1024 - PITCH / 4)) * 4;
        *(float4*)&buf0[H * PITCH + j] = z4;
        *(float4*)&buf1[H * PITCH + j] = z4;
    }

    // ---- stage first plane into buf0 ----
    {
        const float4* src = (const float4*)(x + (size_t)(b * C + c0) * HW);
        float4 r0 = src[tid];
        float4 r1 = src[1024 + tid];
        float4 r2 = src[2048 + tid];
        float4 r3 = src[3072 + tid];
        #pragma unroll
        for (int i = 0; i < 4; ++i) {
            const int m = i * 1024 + tid;
            const float4 v = (i == 0) ? r0 : (i == 1) ? r1 : (i == 2) ? r2 : r3;
            *(float4*)&buf0[(m >> 5) * PITCH + ((m & 31) << 2)] = v;
        }
    }
    __syncthreads();   // table + pads + first plane visible

    float* cur = buf0;
    float* nxt = buf1;

    #pragma unroll 1
    for (int p = 0; p < PLANES_PER_BLOCK; ++p) {
        // -- issue next plane's loads now; they fly during compute --
        float4 r0, r1, r2, r3;
        if (p < PLANES_PER_BLOCK - 1) {
            const float4* src = (const float4*)(x + (size_t)(b * C + c0 + p + 1) * HW);
            r0 = src[tid];
            r1 = src[1024 + tid];
            r2 = src[2048 + tid];
            r3 = src[3072 + tid];
        }

        // -- compute current plane: 2304 outputs, <=3 per thread --
        const int c = c0 + p;
        float* ob = out + ((size_t)(b * NBOX) * C + c) * NBINS;
        #pragma unroll 1
        for (int it = 0; it < 3; ++it) {
            const int k = it * 1024 + tid;
            if (k < NOUT) {
                const int n = k / NBINS;
                const int bin = k - n * NBINS;
                const int oh = bin / OUT_W;
                const int ow = bin - oh * OUT_W;
                const float4* e = stab + n * ENT_PER_BOX;

                const float4 ty0 = e[oh * 2 + 0];
                const float4 ty1 = e[oh * 2 + 1];
                const float4 tx0 = e[12 + ow * 2 + 0];
                const float4 tx1 = e[12 + ow * 2 + 1];
                const int xl0 = (int)tx0.z, xl1 = (int)tx1.z;

                const float* a0 = cur + (int)ty0.z * PITCH;
                const float* a1 = a0 + PITCH;    // pad row if yl==127 (ty0.y==0 then)
                float acc = ty0.x * (tx0.x * a0[xl0] + tx0.y * a0[xl0 + 1])
                          + ty0.y * (tx0.x * a1[xl0] + tx0.y * a1[xl0 + 1])
                          + ty0.x * (tx1.x * a0[xl1] + tx1.y * a0[xl1 + 1])
                          + ty0.y * (tx1.x * a1[xl1] + tx1.y * a1[xl1 + 1]);

                const float* q0 = cur + (int)ty1.z * PITCH;
                const float* q1 = q0 + PITCH;
                acc += ty1.x * (tx0.x * q0[xl0] + tx0.y * q0[xl0 + 1])
                     + ty1.y * (tx0.x * q1[xl0] + tx0.y * q1[xl0 + 1])
                     + ty1.x * (tx1.x * q0[xl1] + tx1.y * q0[xl1 + 1])
                     + ty1.y * (tx1.x * q1[xl1] + tx1.y * q1[xl1 + 1]);

                ob[(size_t)n * (C * NBINS) + bin] = acc * 0.25f;
            }
        }
        __syncthreads();   // all reads of `nxt`'s previous contents long done;
                           // all reads of `cur` this plane done
        if (p < PLANES_PER_BLOCK - 1) {
            #pragma unroll
            for (int i = 0; i < 4; ++i) {
                const int m = i * 1024 + tid;
                const float4 v = (i == 0) ? r0 : (i == 1) ? r1 : (i == 2) ? r2 : r3;
                *(float4*)&nxt[(m >> 5) * PITCH + ((m & 31) << 2)] = v;
            }
        }
        __syncthreads();   // nxt ready for next iteration
        float* t = cur; cur = nxt; nxt = t;
    }
}

extern "C" void kernel_launch(void* const* d_in, const int* in_sizes, int n_in,
                              void* d_out, int out_size, void* d_ws, size_t ws_size,
                              hipStream_t stream) {
    const float* x     = (const float*)d_in[0];
    const float* boxes = (const float*)d_in[1];
    float* out = (float*)d_out;

    roi_persist_kernel<<<NBLK, 1024, 0, stream>>>(x, boxes, out);
}